// Round 7
// baseline (102.622 us; speedup 1.0000x reference)
//
#include <hip/hip_runtime.h>
#include <math.h>

#define NTHREADS 256
#define M_S 50      // samples on ellipse
#define N_PTS 2048  // targets per view
#define PROWS 64    // one partial row per quad (256 threads / 4)
#define PCOLS 52    // 50 samples padded to 52 (16B-aligned rows, bank spread)

typedef float v2f __attribute__((ext_vector_type(2)));
__device__ __forceinline__ v2f splat2(float x) { return (v2f){x, x}; }

// quad-local min via DPP quad_perm (pure VALU, no DS pipe, ~4cy latency)
__device__ __forceinline__ float qmin_x1(float x) {
    int t = __builtin_amdgcn_update_dpp(0, __float_as_int(x), 0xB1 /*[1,0,3,2]*/, 0xF, 0xF, true);
    return fminf(x, __int_as_float(t));
}
__device__ __forceinline__ float qmin_x2(float x) {
    int t = __builtin_amdgcn_update_dpp(0, __float_as_int(x), 0x4E /*[2,3,0,1]*/, 0xF, 0xF, true);
    return fminf(x, __int_as_float(t));
}

__global__ __launch_bounds__(NTHREADS, 8) void chamfer_ellipse_kernel(
    const float* __restrict__ u,     // (1,6): r0,r1,r2, ax,ay,az
    const float* __restrict__ rot,   // (V,3,3)
    const float* __restrict__ tgt,   // (V,N,2)
    float* __restrict__ out)         // (V,)
{
    const int v    = blockIdx.x;
    const int tid  = threadIdx.x;
    const int lane = tid & 63;
    const int wid  = tid >> 6;

    __shared__ float4 samp[M_S];          // (-2sx, -2sy, sx^2+sy^2, 0)
    __shared__ float  part[PROWS][PCOLS]; // per-quad sample mins (13.3 KB)
    __shared__ float  wave_ysum[4];

    // ---- issue the 8-targets-per-thread global loads early (latency hide) ----
    const float4* tp = reinterpret_cast<const float4*>(tgt + (size_t)v * (N_PTS * 2));
    float4 t0 = tp[tid];
    float4 t1 = tp[tid + 256];
    float4 t2 = tp[tid + 512];
    float4 t3 = tp[tid + 768];

    // ---- per-view setup, redundantly in threads 0..49 ----
    if (tid < M_S) {
        float r0 = u[0], r1 = u[1], r2 = u[2];
        float ax = u[3], ay = u[4], az = u[5];
        float l0 = 1.0f / (r0 * r0), l1 = 1.0f / (r1 * r1), l2 = 1.0f / (r2 * r2);
        float cx = cosf(ax), sx = sinf(ax);
        float cy = cosf(ay), sy = sinf(ay);
        float cz = cosf(az), sz = sinf(az);
        // Q = Rz @ Ry @ Rx
        float q00 = cz * cy, q01 = cz * sy * sx - sz * cx, q02 = cz * sy * cx + sz * sx;
        float q10 = sz * cy, q11 = sz * sy * sx + cz * cx, q12 = sz * sy * cx - cz * sx;
        float q20 = -sy,     q21 = cy * sx,                q22 = cy * cx;
        // A = Q diag(l) Q^T (symmetric)
        float A00 = q00 * q00 * l0 + q01 * q01 * l1 + q02 * q02 * l2;
        float A01 = q00 * q10 * l0 + q01 * q11 * l1 + q02 * q12 * l2;
        float A02 = q00 * q20 * l0 + q01 * q21 * l1 + q02 * q22 * l2;
        float A11 = q10 * q10 * l0 + q11 * q11 * l1 + q12 * q12 * l2;
        float A12 = q10 * q20 * l0 + q11 * q21 * l1 + q12 * q22 * l2;
        float A22 = q20 * q20 * l0 + q21 * q21 * l1 + q22 * q22 * l2;
        // R (per view)
        const float* Rv = rot + v * 9;
        float R00 = Rv[0], R01 = Rv[1], R02 = Rv[2];
        float R10 = Rv[3], R11 = Rv[4], R12 = Rv[5];
        float R20 = Rv[6], R21 = Rv[7], R22 = Rv[8];
        // T = R A  (A symmetric)
        float T00 = R00 * A00 + R01 * A01 + R02 * A02;
        float T01 = R00 * A01 + R01 * A11 + R02 * A12;
        float T02 = R00 * A02 + R01 * A12 + R02 * A22;
        float T10 = R10 * A00 + R11 * A01 + R12 * A02;
        float T11 = R10 * A01 + R11 * A11 + R12 * A12;
        float T12 = R10 * A02 + R11 * A12 + R12 * A22;
        float T20 = R20 * A00 + R21 * A01 + R22 * A02;
        float T21 = R20 * A01 + R21 * A11 + R22 * A12;
        float T22 = R20 * A02 + R21 * A12 + R22 * A22;
        // M = T R^T (symmetric)
        float Ma = T00 * R00 + T01 * R01 + T02 * R02;
        float Mb = T00 * R10 + T01 * R11 + T02 * R12;
        float Mc = T00 * R20 + T01 * R21 + T02 * R22;
        float Md = T10 * R00 + T11 * R01 + T12 * R02;
        float Me = T10 * R10 + T11 * R11 + T12 * R12;
        float Mf = T10 * R20 + T11 * R21 + T12 * R22;
        float Mg = T20 * R00 + T21 * R01 + T22 * R02;
        float Mh = T20 * R10 + T21 * R11 + T22 * R12;
        float Mi = T20 * R20 + T21 * R21 + T22 * R22;
        // top-left 2x2 of M^-1 via adjugate
        float c00 = Me * Mi - Mf * Mh;
        float c01 = Mc * Mh - Mb * Mi;
        float c10 = Mf * Mg - Md * Mi;
        float c11 = Ma * Mi - Mc * Mg;
        float det = Ma * c00 + Mb * c10 + Mc * (Md * Mh - Me * Mg);
        float idet = 1.0f / det;
        float p = c00 * idet, q = c01 * idet, r = c10 * idet, s = c11 * idet;
        // C = inv(B2)
        float idet2 = 1.0f / (p * s - q * r);
        float C00 = s * idet2, C10 = -r * idet2, C11 = p * idet2;
        // lower Cholesky of C; U = L^T
        float L00 = sqrtf(C00);
        float L10 = C10 / L00;
        float L11 = sqrtf(C11 - L10 * L10);
        // U^-1 (upper tri): [[1/L00, -L10/(L00*L11)],[0, 1/L11]]
        float iu00 = 1.0f / L00;
        float iu11 = 1.0f / L11;
        float iu01 = -L10 * iu00 * iu11;
        // sample point m = tid
        float t  = 6.283185307179586f * ((float)tid * (1.0f / 49.0f));
        float ct = cosf(t), st = sinf(t);
        float sxp = iu00 * ct + iu01 * st;
        float syp = iu11 * st;
        samp[tid] = make_float4(-2.0f * sxp, -2.0f * syp, sxp * sxp + syp * syp, 0.0f);
    }
    __syncthreads();

    // ---- register-resident targets, packed pairwise for v_pk_* ----
    v2f TX[4], TY[4], YY2[4];
    TX[0] = (v2f){t0.x, t0.z};  TY[0] = (v2f){t0.y, t0.w};
    TX[1] = (v2f){t1.x, t1.z};  TY[1] = (v2f){t1.y, t1.w};
    TX[2] = (v2f){t2.x, t2.z};  TY[2] = (v2f){t2.y, t2.w};
    TX[3] = (v2f){t3.x, t3.z};  TY[3] = (v2f){t3.y, t3.w};
    float ym[8];
#pragma unroll
    for (int p = 0; p < 4; ++p) {
        YY2[p] = __builtin_elementwise_fma(TX[p], TX[p], TY[p] * TY[p]);
        ym[2 * p]     = INFINITY;
        ym[2 * p + 1] = INFINITY;
    }

    // ---- main chamfer loop: 25 pairs of samples, packed fp32 d2 ----
    const int  prow   = tid >> 2;            // one partial row per quad
    const bool writer = ((lane & 3) == 0);
    for (int g = 0; g < 25; ++g) {
        float4 sp0 = samp[2 * g];
        float4 sp1 = samp[2 * g + 1];
        v2f x0 = splat2(sp0.x), y0 = splat2(sp0.y), z0 = splat2(sp0.z);
        v2f x1 = splat2(sp1.x), y1 = splat2(sp1.y), z1 = splat2(sp1.z);
        v2f e0[4], e1[4];
#pragma unroll
        for (int p = 0; p < 4; ++p) {
            v2f c0 = YY2[p] + z0;                                  // v_pk_add_f32
            v2f c1 = YY2[p] + z1;
            e0[p] = __builtin_elementwise_fma(x0, TX[p],
                      __builtin_elementwise_fma(y0, TY[p], c0));   // v_pk_fma_f32 x2
            e1[p] = __builtin_elementwise_fma(x1, TX[p],
                      __builtin_elementwise_fma(y1, TY[p], c1));
        }
        // per-target running min over both samples (min3-fusable, scalar halves)
#pragma unroll
        for (int p = 0; p < 4; ++p) {
            ym[2 * p]     = fminf(fminf(ym[2 * p],     e0[p].x), e1[p].x);
            ym[2 * p + 1] = fminf(fminf(ym[2 * p + 1], e0[p].y), e1[p].y);
        }
        // per-sample tree mins over the 8 targets (min3-fusable)
        float m0 = fminf(fminf(fminf(fminf(e0[0].x, e0[0].y), e0[1].x),
                               fminf(fminf(e0[1].y, e0[2].x), e0[2].y)),
                         fminf(e0[3].x, e0[3].y));
        float m1 = fminf(fminf(fminf(fminf(e1[0].x, e1[0].y), e1[1].x),
                               fminf(fminf(e1[1].y, e1[2].x), e1[2].y)),
                         fminf(e1[3].x, e1[3].y));
        // quad reduction on the VALU pipe (DPP), lane&3==0 parks partials
        m0 = qmin_x2(qmin_x1(m0));
        m1 = qmin_x2(qmin_x1(m1));
        if (writer) {
            part[prow][2 * g]     = m0;   // adjacent -> ds_write_b64
            part[prow][2 * g + 1] = m1;
        }
    }

    // ---- cham_y: sum of per-target mins ----
    float ysum = 0.0f;
#pragma unroll
    for (int j = 0; j < 8; ++j) ysum += ym[j];
#pragma unroll
    for (int off = 32; off > 0; off >>= 1) ysum += __shfl_xor(ysum, off);
    if (lane == 0) wave_ysum[wid] = ysum;
    __syncthreads();

    // ---- cham_x: reduce 64 quad-partials per sample (threads 0..49) ----
    if (wid == 0) {
        float val = 0.0f;
        if (lane < M_S) {
            float m = INFINITY;
#pragma unroll 8
            for (int j = 0; j < PROWS; ++j)
                m = fminf(m, part[j][lane]);
            val = m;
        }
#pragma unroll
        for (int off = 32; off > 0; off >>= 1) val += __shfl_xor(val, off);
        if (lane == 0) {
            float ysum_tot = wave_ysum[0] + wave_ysum[1] + wave_ysum[2] + wave_ysum[3];
            out[v] = val * (1.0f / (float)M_S) + ysum_tot * (1.0f / (float)N_PTS);
        }
    }
}

extern "C" void kernel_launch(void* const* d_in, const int* in_sizes, int n_in,
                              void* d_out, int out_size, void* d_ws, size_t ws_size,
                              hipStream_t stream) {
    const float* u   = (const float*)d_in[0];
    const float* rot = (const float*)d_in[1];
    const float* tgt = (const float*)d_in[2];
    float* out = (float*)d_out;

    const int V = in_sizes[1] / 9;  // 2048
    chamfer_ellipse_kernel<<<V, NTHREADS, 0, stream>>>(u, rot, tgt, out);
}